// Round 1
// 303.906 us; speedup vs baseline: 1.0040x; 1.0040x over previous
//
#include <hip/hip_runtime.h>
#include <hip/hip_bf16.h>
#include <cstdint>

// KAN MLP: 256->512->512->256, B=8192, cubic B-splines (uniform grid h=0.25,
// knots -1.75..1.75, 11 bases), BN at the end.
//
// Round-5: GEMM rebuilt as 8-wave deep pipeline (T3+T4+T5 from the CDNA4
// catalog). Previous round's m97-style 128x128/4-wave GEMM measured 838 TF
// (MfmaUtil 33.6%) == that structure's known ~900 TF ceiling (vmcnt(0)
// drain at every __syncthreads). New structure:
//   - tile 128(M) x 256(N), BK=64, 512 threads = 8 waves (2M x 4N),
//     wave = 64x64 (acc[4][4] of 16x16x32 bf16 MFMA)
//   - TRIPLE-buffered LDS (3 x 48 KB = 144 KB), stage tile t+2 during tile t
//   - counted s_waitcnt vmcnt(6) at tile boundary (never 0 in steady state),
//     raw s_barrier (no compiler vmcnt(0) drain)
//   - 4 phases per K-tile: {stage-issue, ds_read subtile, barrier,
//     lgkmcnt(0), setprio(1), 8 MFMA, setprio(0), barrier}
//   - round-1 LDS chunk-XOR swizzle kept (measured ZERO bank conflicts)
// Grids: L0 (64,2,2), L1 (64,2,2), L2 (64,1,4) -> exactly 256 blocks
// = 1 block/CU, 2 waves/SIMD. Split-K + workspace layout unchanged.
//
// Workspace (146,800,640 bytes total -- proven available):
//   A   @ 0          : 8192*6144*2 = 100,663,296 (reused all layers)
//   W0  @ 100663296  : 3,145,728
//   W1  @ 103809024  : 6,291,456
//   W2  @ 110100480  : 3,145,728
//   P   @ 113246208  : L0/L1: 2 x 16MB fp32 partials; L2: 4 x 8MB partials

typedef unsigned short ushort_t;
typedef __bf16 bf16x8 __attribute__((ext_vector_type(8)));
typedef float f32x4 __attribute__((ext_vector_type(4)));

__device__ __forceinline__ ushort_t f2bf(float f) {
    __bf16 h = (__bf16)f;  // RNE
    return __builtin_bit_cast(ushort_t, h);
}

// async global->LDS 16B copy; LDS dest must be wave-uniform base + lane*16.
__device__ __forceinline__ void gload_lds16(const void* g, void* lds) {
    __builtin_amdgcn_global_load_lds(
        (const __attribute__((address_space(1))) unsigned int*)(uintptr_t)g,
        (__attribute__((address_space(3))) unsigned int*)(unsigned int)(uintptr_t)lds,
        16, 0, 0);
}

// x -> [gelu, b0..b10] (12 bf16). Direct cardinal cubic B-spline:
// basis_j(x) = b(xs - j), xs=(x+1.75)*4;  b(t), a=|t-2|:
//   a<=1: (4-6a^2+3a^3)/6 ; 1<a<2: (2-a)^3/6 ; else 0.
__device__ __forceinline__ void expand12(float x, ushort_t* o) {
    float x3 = x * x * x;
    float y  = 0.7978845608028654f * (x + 0.044715f * x3);
    float e  = __expf(2.0f * y);
    float th = 1.0f - 2.0f / (e + 1.0f);       // tanh(y)
    o[0] = f2bf(0.5f * x * (1.0f + th));
    float xs = (x + 1.75f) * 4.0f;
#pragma unroll
    for (int j = 0; j < 11; ++j) {
        float t  = xs - (float)j;
        float a  = fabsf(t - 2.0f);
        float p1 = (3.0f * a - 6.0f) * a * a + 4.0f;   // a<=1 branch
        float c  = 2.0f - a;
        float p2 = c * c * c;                          // 1<a<2 branch
        float v  = (a <= 1.0f) ? p1 : fmaxf(p2, 0.0f);
        o[1 + j] = f2bf(v * (1.0f / 6.0f));
    }
}

// ---------------------------------------------------------------------------
// Expansion: 2 elements/thread; optionally sums two partials (previous
// layer's split-K reduction fused in). Writes 48 B/thread.
// ---------------------------------------------------------------------------
template <bool SUM>
__global__ __launch_bounds__(256) void expand_kernel(
    const float* __restrict__ X0, const float* __restrict__ X1,
    ushort_t* __restrict__ A, int total2)
{
    int idx = blockIdx.x * 256 + threadIdx.x;
    if (idx >= total2) return;
    float2 h = *(const float2*)(X0 + 2 * (size_t)idx);
    if (SUM) {
        float2 h2 = *(const float2*)(X1 + 2 * (size_t)idx);
        h.x += h2.x; h.y += h2.y;
    }
    union { ushort_t us[24]; uint4 v[3]; } pk;
    expand12(h.x, pk.us);
    expand12(h.y, pk.us + 12);
    uint4* dst = (uint4*)(A + (size_t)idx * 24);
    dst[0] = pk.v[0]; dst[1] = pk.v[1]; dst[2] = pk.v[2];
}

// ---------------------------------------------------------------------------
// Weight pack (row-major): W[o][i*12+0]=base_w[o][i]; W[o][i*12+1+k]=spline_w.
// ---------------------------------------------------------------------------
__global__ __launch_bounds__(256) void pack_w_kernel(
    const float* __restrict__ bw, const float* __restrict__ sw,
    ushort_t* __restrict__ W, int total)
{
    int idx = blockIdx.x * 256 + threadIdx.x;
    if (idx >= total) return;
    union { ushort_t us[12]; uint2 v[3]; } pk;
    pk.us[0] = f2bf(bw[idx]);
    const float* s = sw + (size_t)idx * 11;
#pragma unroll
    for (int k = 0; k < 11; ++k) pk.us[1 + k] = f2bf(s[k]);
    uint2* dst = (uint2*)(W + (size_t)idx * 12);
    dst[0] = pk.v[0]; dst[1] = pk.v[1]; dst[2] = pk.v[2];
}

// ---------------------------------------------------------------------------
// GEMM: C_z[M,N] = A[M,kslice] @ W[N,kslice]^T (bf16 in, fp32 out).
// Tile 128x256, BK=64, 8 waves 2Mx4N, wave = 64x64 (4x4 of 16x16x32 MFMA).
// LDS: 3 slots of {A 128x64 (16KB) | B 256x64 (32KB)}; rows stored as 8
// chunks of 16B, physical chunk = logical ^ (row&7) (round-1 swizzle,
// measured 0 bank conflicts).
//   A frag: lane holds A[m=l15][k=kc*8+j], kc=ks*4+q;  C/D: D[m=q*4+r][n=l15].
// Pipeline: stage tile t+2 into slot (t+2)%3 during tile t's 4 phases
// (2+2+2 gload_lds16/thread), boundary wait = vmcnt(6), raw s_barrier.
// Split-K over blockIdx.z -> C + z*M*N.
// ---------------------------------------------------------------------------
#define SLOT 24576   // elements per LDS slot (48 KB)
#define ASZ  8192    // A-tile elements within a slot (16 KB)

__global__ __launch_bounds__(512, 2) void gemm_kernel(
    const ushort_t* __restrict__ A,  // M x K
    const ushort_t* __restrict__ W,  // N x K
    float* __restrict__ C,           // split-K partials, z*M*N apart
    int M, int N, int K, int kcps)   // kcps = 64-chunks per split (>= 2)
{
    extern __shared__ __align__(16) ushort_t lds[];   // 3*SLOT = 144 KB

    const int t   = threadIdx.x;
    const int l   = t & 63;
    const int w   = t >> 6;        // 0..7
    const int wm  = w >> 2;        // 0..1  (M half)
    const int wn  = w & 3;         // 0..3  (N quarter)
    const int l15 = l & 15;
    const int q   = l >> 4;        // 0..3
    const int blockM = blockIdx.x * 128;
    const int blockN = blockIdx.y * 256;
    const int kb0 = blockIdx.z * kcps;
    const int nt  = kcps;
    float* Cz = C + (size_t)blockIdx.z * M * N;

    const ushort_t* Ab = A + (size_t)blockM * K;
    const ushort_t* Wb = W + (size_t)blockN * K;

    // A staging: 128 rows x 8 chunks = 1024 chunk-slots, 2/thread.
    auto stage_a = [&](int kb, ushort_t* dst) {
#pragma unroll
        for (int it = 0; it < 2; ++it) {
            int s   = it * 512 + t;
            int row = s >> 3, c = s & 7;
            int g   = c ^ (row & 7);
            gload_lds16(Ab + ((size_t)row * K + (kb << 6) + g * 8), dst + s * 8);
        }
    };
    // B staging: 256 rows x 8 chunks = 2048 chunk-slots, 4/thread, two halves.
    auto stage_b = [&](int kb, ushort_t* dst, int half) {
#pragma unroll
        for (int it = 0; it < 2; ++it) {
            int s   = (half * 2 + it) * 512 + t;
            int row = s >> 3, c = s & 7;
            int g   = c ^ (row & 7);
            gload_lds16(Wb + ((size_t)row * K + (kb << 6) + g * 8), dst + s * 8);
        }
    };

    f32x4 acc[4][4];
#pragma unroll
    for (int i = 0; i < 4; ++i)
#pragma unroll
        for (int j = 0; j < 4; ++j) acc[i][j] = (f32x4){0.f, 0.f, 0.f, 0.f};

    // prologue: stage tiles kb0 and kb0+1 into slots 0 and 1 (nt >= 2 always)
    stage_a(kb0, lds);            stage_b(kb0, lds + ASZ, 0);       stage_b(kb0, lds + ASZ, 1);
    stage_a(kb0 + 1, lds + SLOT); stage_b(kb0 + 1, lds + SLOT + ASZ, 0);
    stage_b(kb0 + 1, lds + SLOT + ASZ, 1);
    asm volatile("s_waitcnt vmcnt(6)" ::: "memory");   // tile 0 resident
    __builtin_amdgcn_s_barrier();

    int cur = 0;
    for (int tt = 0; tt < nt; ++tt) {
        ushort_t* Ac = lds + cur * SLOT;
        ushort_t* Bc = Ac + ASZ;
        int nx = cur + 2; if (nx >= 3) nx -= 3;
        ushort_t* An = lds + nx * SLOT;
        ushort_t* Bn = An + ASZ;
        const bool pre = (tt + 2 < nt);
        const int  kbp = kb0 + tt + 2;

        bf16x8 af[2], bf[4];

        // -------- phase 1: ks=0, mi in {0,1} --------
        if (pre) stage_a(kbp, An);
        {
            const int kc = q;          // chunk within BK for ks=0
#pragma unroll
            for (int ni = 0; ni < 4; ++ni) {
                int n = wn * 64 + ni * 16 + l15;
                bf[ni] = *(const bf16x8*)&Bc[(n * 8 + (kc ^ (n & 7))) * 8];
            }
#pragma unroll
            for (int mi = 0; mi < 2; ++mi) {
                int m = wm * 64 + mi * 16 + l15;
                af[mi] = *(const bf16x8*)&Ac[(m * 8 + (kc ^ (m & 7))) * 8];
            }
        }
        __builtin_amdgcn_s_barrier();
        asm volatile("s_waitcnt lgkmcnt(0)" ::: "memory");
        __builtin_amdgcn_s_setprio(1);
#pragma unroll
        for (int mi = 0; mi < 2; ++mi)
#pragma unroll
            for (int ni = 0; ni < 4; ++ni)
                acc[mi][ni] = __builtin_amdgcn_mfma_f32_16x16x32_bf16(
                    af[mi], bf[ni], acc[mi][ni], 0, 0, 0);
        __builtin_amdgcn_s_setprio(0);
        __builtin_amdgcn_s_barrier();

        // -------- phase 2: ks=0, mi in {2,3} (reuse bf) --------
        if (pre) stage_b(kbp, Bn, 0);
        {
            const int kc = q;
#pragma unroll
            for (int mi = 0; mi < 2; ++mi) {
                int m = wm * 64 + (mi + 2) * 16 + l15;
                af[mi] = *(const bf16x8*)&Ac[(m * 8 + (kc ^ (m & 7))) * 8];
            }
        }
        __builtin_amdgcn_s_barrier();
        asm volatile("s_waitcnt lgkmcnt(0)" ::: "memory");
        __builtin_amdgcn_s_setprio(1);
#pragma unroll
        for (int mi = 0; mi < 2; ++mi)
#pragma unroll
            for (int ni = 0; ni < 4; ++ni)
                acc[mi + 2][ni] = __builtin_amdgcn_mfma_f32_16x16x32_bf16(
                    af[mi], bf[ni], acc[mi + 2][ni], 0, 0, 0);
        __builtin_amdgcn_s_setprio(0);
        __builtin_amdgcn_s_barrier();

        // -------- phase 3: ks=1, mi in {0,1} --------
        if (pre) stage_b(kbp, Bn, 1);
        {
            const int kc = 4 + q;      // chunk within BK for ks=1
#pragma unroll
            for (int ni = 0; ni < 4; ++ni) {
                int n = wn * 64 + ni * 16 + l15;
                bf[ni] = *(const bf16x8*)&Bc[(n * 8 + (kc ^ (n & 7))) * 8];
            }
#pragma unroll
            for (int mi = 0; mi < 2; ++mi) {
                int m = wm * 64 + mi * 16 + l15;
                af[mi] = *(const bf16x8*)&Ac[(m * 8 + (kc ^ (m & 7))) * 8];
            }
        }
        __builtin_amdgcn_s_barrier();
        asm volatile("s_waitcnt lgkmcnt(0)" ::: "memory");
        __builtin_amdgcn_s_setprio(1);
#pragma unroll
        for (int mi = 0; mi < 2; ++mi)
#pragma unroll
            for (int ni = 0; ni < 4; ++ni)
                acc[mi][ni] = __builtin_amdgcn_mfma_f32_16x16x32_bf16(
                    af[mi], bf[ni], acc[mi][ni], 0, 0, 0);
        __builtin_amdgcn_s_setprio(0);
        __builtin_amdgcn_s_barrier();

        // -------- phase 4: ks=1, mi in {2,3} (reuse bf) --------
        {
            const int kc = 4 + q;
#pragma unroll
            for (int mi = 0; mi < 2; ++mi) {
                int m = wm * 64 + (mi + 2) * 16 + l15;
                af[mi] = *(const bf16x8*)&Ac[(m * 8 + (kc ^ (m & 7))) * 8];
            }
        }
        __builtin_amdgcn_s_barrier();
        asm volatile("s_waitcnt lgkmcnt(0)" ::: "memory");
        __builtin_amdgcn_s_setprio(1);
#pragma unroll
        for (int mi = 0; mi < 2; ++mi)
#pragma unroll
            for (int ni = 0; ni < 4; ++ni)
                acc[mi + 2][ni] = __builtin_amdgcn_mfma_f32_16x16x32_bf16(
                    af[mi], bf[ni], acc[mi + 2][ni], 0, 0, 0);
        __builtin_amdgcn_s_setprio(0);
        // tile boundary: keep tile t+2's 6 loads in flight; require t+1 done.
        if (pre) asm volatile("s_waitcnt vmcnt(6)" ::: "memory");
        else     asm volatile("s_waitcnt vmcnt(0)" ::: "memory");
        __builtin_amdgcn_s_barrier();

        cur = cur + 1; if (cur == 3) cur = 0;
    }

    // epilogue: coalesced stores into this split's partial buffer
#pragma unroll
    for (int ni = 0; ni < 4; ++ni) {
        int n = blockN + wn * 64 + ni * 16 + l15;
#pragma unroll
        for (int mi = 0; mi < 4; ++mi) {
            int mb = blockM + wm * 64 + mi * 16 + q * 4;
#pragma unroll
            for (int r = 0; r < 4; ++r)
                Cz[(size_t)(mb + r) * N + n] = acc[mi][ni][r];
        }
    }
}

// ---------------------------------------------------------------------------
// Final: out = gamma*rsqrt(var+eps)*(Q0+Q1+Q2+Q3 - mean) + beta, N=256 cols.
// ---------------------------------------------------------------------------
__global__ __launch_bounds__(256) void bn_reduce_kernel(
    const float4* __restrict__ Q0, const float4* __restrict__ Q1,
    const float4* __restrict__ Q2, const float4* __restrict__ Q3,
    const float* __restrict__ gamma, const float* __restrict__ beta,
    const float* __restrict__ mean,  const float* __restrict__ var,
    float4* __restrict__ out, int n4)
{
    int i = blockIdx.x * 256 + threadIdx.x;
    if (i >= n4) return;
    float4 a = Q0[i], b = Q1[i], c = Q2[i], d = Q3[i];
    int nb = (i * 4) & 255;
    float4 g  = *(const float4*)(gamma + nb);
    float4 be = *(const float4*)(beta + nb);
    float4 mn = *(const float4*)(mean + nb);
    float4 vr = *(const float4*)(var + nb);
    float4 o;
    o.x = g.x * rsqrtf(vr.x + 1e-5f) * (a.x + b.x + c.x + d.x - mn.x) + be.x;
    o.y = g.y * rsqrtf(vr.y + 1e-5f) * (a.y + b.y + c.y + d.y - mn.y) + be.y;
    o.z = g.z * rsqrtf(vr.z + 1e-5f) * (a.z + b.z + c.z + d.z - mn.z) + be.z;
    o.w = g.w * rsqrtf(vr.w + 1e-5f) * (a.w + b.w + c.w + d.w - mn.w) + be.w;
    out[i] = o;
}

// ---------------------------------------------------------------------------
extern "C" void kernel_launch(void* const* d_in, const int* in_sizes, int n_in,
                              void* d_out, int out_size, void* d_ws, size_t ws_size,
                              hipStream_t stream) {
    const float* x     = (const float*)d_in[0];
    const float* bw0   = (const float*)d_in[2];
    const float* sw0   = (const float*)d_in[3];
    const float* bw1   = (const float*)d_in[5];
    const float* sw1   = (const float*)d_in[6];
    const float* bw2   = (const float*)d_in[8];
    const float* sw2   = (const float*)d_in[9];
    const float* gamma = (const float*)d_in[10];
    const float* beta  = (const float*)d_in[11];
    const float* mean  = (const float*)d_in[12];
    const float* var   = (const float*)d_in[13];

    char* ws = (char*)d_ws;
    ushort_t* Abuf = (ushort_t*)(ws);
    ushort_t* W0   = (ushort_t*)(ws + 100663296);
    ushort_t* W1   = (ushort_t*)(ws + 103809024);
    ushort_t* W2   = (ushort_t*)(ws + 110100480);
    float*    P0   = (float*)(ws + 113246208);   // 16 MB (L0/L1 partials)
    float*    P1   = (float*)(ws + 130023424);   // 16 MB
    float*    Q0   = (float*)(ws + 113246208);   // 8 MB (L2 partials x4)
    float*    Q1   = (float*)(ws + 121634816);
    float*    Q2   = (float*)(ws + 130023424);
    float*    Q3   = (float*)(ws + 138412032);
    float*    out  = (float*)d_out;

    const size_t GEMM_LDS = 3 * SLOT * sizeof(ushort_t);  // 147456 B

    // weight packing (d_ws re-poisoned every call -> repack)
    pack_w_kernel<<<(512 * 256 + 255) / 256, 256, 0, stream>>>(bw0, sw0, W0, 512 * 256);
    pack_w_kernel<<<(512 * 512 + 255) / 256, 256, 0, stream>>>(bw1, sw1, W1, 512 * 512);
    pack_w_kernel<<<(256 * 512 + 255) / 256, 256, 0, stream>>>(bw2, sw2, W2, 256 * 512);

    // layer 0: K=3072 (48 chunks, 24/split), N=512, SK=2
    expand_kernel<false><<<4096, 256, 0, stream>>>(x, nullptr, Abuf, 8192 * 256 / 2);
    {
        dim3 g(64, 2, 2);
        gemm_kernel<<<g, 512, GEMM_LDS, stream>>>(Abuf, W0, P0, 8192, 512, 3072, 24);
    }
    // layer 1: K=6144 (96 chunks, 48/split), N=512, SK=2
    expand_kernel<true><<<8192, 256, 0, stream>>>(P0, P1, Abuf, 8192 * 512 / 2);
    {
        dim3 g(64, 2, 2);
        gemm_kernel<<<g, 512, GEMM_LDS, stream>>>(Abuf, W1, P0, 8192, 512, 6144, 48);
    }
    // layer 2: K=6144 (96 chunks, 24/split), N=256, SK=4
    expand_kernel<true><<<8192, 256, 0, stream>>>(P0, P1, Abuf, 8192 * 512 / 2);
    {
        dim3 g(64, 1, 4);
        gemm_kernel<<<g, 512, GEMM_LDS, stream>>>(Abuf, W2, Q0, 8192, 256, 6144, 24);
    }
    // BN + split-K reduce -> out
    bn_reduce_kernel<<<2048, 256, 0, stream>>>(
        (const float4*)Q0, (const float4*)Q1, (const float4*)Q2, (const float4*)Q3,
        gamma, beta, mean, var, (float4*)out, 8192 * 256 / 4);
}

// Round 2
// 297.343 us; speedup vs baseline: 1.0262x; 1.0221x over previous
//
#include <hip/hip_runtime.h>
#include <hip/hip_bf16.h>
#include <cstdint>

// KAN MLP: 256->512->512->256, B=8192, cubic B-splines (uniform grid h=0.25,
// knots -1.75..1.75, 11 bases), BN at the end.
//
// Round-6: round-5's 8-phase port was NEUTRAL (31% MfmaUtil) because the
// wave tile (64x64) costs 512 B LDS-read per MFMA = over the LDS BW ceiling;
// phases just serialize DS vs MFMA. Fix is GEOMETRY: wave tile 128x64
// (256 B/MFMA, 12 ds_read_b128 per 32 MFMA) via in-block K-split:
//   - tile 128(M) x 256(N), BK=64, 512 threads = 8 waves (kg,wn)
//   - wave (kg,wn): ALL 128 rows x 64-col quarter wn, k-half kg of each
//     BK tile (kc = kg*4+q); acc[8][4]
//   - kg=0/1 wave pairs summed through LDS (fp32, padded) in epilogue
//   - triple-buffered LDS (3 x 48 KB = 144 KB), stage tile t+2 during t
//   - ONE raw s_barrier + counted vmcnt(6) per K-tile (round-5 proved the
//     per-phase barrier storm is worthless at this ratio; compiler emits
//     fine-grained lgkmcnt for ds_read->MFMA)
//   - round-1 LDS chunk-XOR swizzle kept (measured ZERO bank conflicts)
// Grids unchanged: L0 (64,2,2), L1 (64,2,2), L2 (64,1,4) = 256 blocks,
// 1 block/CU, 2 waves/SIMD. Split-K + workspace layout unchanged.
//
// Workspace (146,800,640 bytes total -- proven available):
//   A   @ 0          : 8192*6144*2 = 100,663,296 (reused all layers)
//   W0  @ 100663296  : 3,145,728
//   W1  @ 103809024  : 6,291,456
//   W2  @ 110100480  : 3,145,728
//   P   @ 113246208  : L0/L1: 2 x 16MB fp32 partials; L2: 4 x 8MB partials

typedef unsigned short ushort_t;
typedef __bf16 bf16x8 __attribute__((ext_vector_type(8)));
typedef float f32x4 __attribute__((ext_vector_type(4)));

__device__ __forceinline__ ushort_t f2bf(float f) {
    __bf16 h = (__bf16)f;  // RNE
    return __builtin_bit_cast(ushort_t, h);
}

// async global->LDS 16B copy; LDS dest must be wave-uniform base + lane*16.
__device__ __forceinline__ void gload_lds16(const void* g, void* lds) {
    __builtin_amdgcn_global_load_lds(
        (const __attribute__((address_space(1))) unsigned int*)(uintptr_t)g,
        (__attribute__((address_space(3))) unsigned int*)(unsigned int)(uintptr_t)lds,
        16, 0, 0);
}

// x -> [gelu, b0..b10] (12 bf16). Direct cardinal cubic B-spline:
// basis_j(x) = b(xs - j), xs=(x+1.75)*4;  b(t), a=|t-2|:
//   a<=1: (4-6a^2+3a^3)/6 ; 1<a<2: (2-a)^3/6 ; else 0.
__device__ __forceinline__ void expand12(float x, ushort_t* o) {
    float x3 = x * x * x;
    float y  = 0.7978845608028654f * (x + 0.044715f * x3);
    float e  = __expf(2.0f * y);
    float th = 1.0f - 2.0f / (e + 1.0f);       // tanh(y)
    o[0] = f2bf(0.5f * x * (1.0f + th));
    float xs = (x + 1.75f) * 4.0f;
#pragma unroll
    for (int j = 0; j < 11; ++j) {
        float t  = xs - (float)j;
        float a  = fabsf(t - 2.0f);
        float p1 = (3.0f * a - 6.0f) * a * a + 4.0f;   // a<=1 branch
        float c  = 2.0f - a;
        float p2 = c * c * c;                          // 1<a<2 branch
        float v  = (a <= 1.0f) ? p1 : fmaxf(p2, 0.0f);
        o[1 + j] = f2bf(v * (1.0f / 6.0f));
    }
}

// ---------------------------------------------------------------------------
// Expansion: 2 elements/thread; optionally sums two partials (previous
// layer's split-K reduction fused in). Writes 48 B/thread.
// ---------------------------------------------------------------------------
template <bool SUM>
__global__ __launch_bounds__(256) void expand_kernel(
    const float* __restrict__ X0, const float* __restrict__ X1,
    ushort_t* __restrict__ A, int total2)
{
    int idx = blockIdx.x * 256 + threadIdx.x;
    if (idx >= total2) return;
    float2 h = *(const float2*)(X0 + 2 * (size_t)idx);
    if (SUM) {
        float2 h2 = *(const float2*)(X1 + 2 * (size_t)idx);
        h.x += h2.x; h.y += h2.y;
    }
    union { ushort_t us[24]; uint4 v[3]; } pk;
    expand12(h.x, pk.us);
    expand12(h.y, pk.us + 12);
    uint4* dst = (uint4*)(A + (size_t)idx * 24);
    dst[0] = pk.v[0]; dst[1] = pk.v[1]; dst[2] = pk.v[2];
}

// ---------------------------------------------------------------------------
// Weight pack (row-major): W[o][i*12+0]=base_w[o][i]; W[o][i*12+1+k]=spline_w.
// ---------------------------------------------------------------------------
__global__ __launch_bounds__(256) void pack_w_kernel(
    const float* __restrict__ bw, const float* __restrict__ sw,
    ushort_t* __restrict__ W, int total)
{
    int idx = blockIdx.x * 256 + threadIdx.x;
    if (idx >= total) return;
    union { ushort_t us[12]; uint2 v[3]; } pk;
    pk.us[0] = f2bf(bw[idx]);
    const float* s = sw + (size_t)idx * 11;
#pragma unroll
    for (int k = 0; k < 11; ++k) pk.us[1 + k] = f2bf(s[k]);
    uint2* dst = (uint2*)(W + (size_t)idx * 12);
    dst[0] = pk.v[0]; dst[1] = pk.v[1]; dst[2] = pk.v[2];
}

// ---------------------------------------------------------------------------
// GEMM: C_z[M,N] = A[M,kslice] @ W[N,kslice]^T (bf16 in, fp32 out).
// Tile 128x256, BK=64, 512 threads = 8 waves indexed (kg = t>>8, wn = (t>>6)&3).
// Wave computes acc[8][4]: rows 0..127, cols wn*64..+63, k-half kg.
// LDS slot: A 128x64 (16KB) + B 256x64 (32KB); rows stored as 8 chunks of
// 16B, physical chunk = logical ^ (row&7) (measured 0 bank conflicts).
//   A frag: lane holds A[m=l15][k=kc*8+j], kc=kg*4+q;  C/D: D[m=q*4+r][n=l15].
// Pipeline: stage tile t+2 into slot (t+2)%3 during tile t (6 loads/thread),
// boundary = lgkmcnt(0) + vmcnt(6) + raw s_barrier (counted, never drains
// the prefetch queue). Epilogue: kg=1 acc -> LDS fp32 -> kg=0 adds + stores.
// Split-K over blockIdx.z -> C + z*M*N.
// ---------------------------------------------------------------------------
#define SLOT 24576   // elements per LDS slot (48 KB)
#define ASZ  8192    // A-tile elements within a slot (16 KB)

__global__ __launch_bounds__(512, 2) void gemm_kernel(
    const ushort_t* __restrict__ A,  // M x K
    const ushort_t* __restrict__ W,  // N x K
    float* __restrict__ C,           // split-K partials, z*M*N apart
    int M, int N, int K, int kcps)   // kcps = 64-chunks per split (>= 2)
{
    extern __shared__ __align__(16) ushort_t lds[];   // 3*SLOT = 144 KB

    const int t   = threadIdx.x;
    const int l   = t & 63;
    const int wn  = (t >> 6) & 3;  // N quarter
    const int kg  = t >> 8;        // k-half group (0/1)
    const int l15 = l & 15;
    const int q   = l >> 4;        // 0..3
    const int blockM = blockIdx.x * 128;
    const int blockN = blockIdx.y * 256;
    const int kb0 = blockIdx.z * kcps;
    const int nt  = kcps;
    float* Cz = C + (size_t)blockIdx.z * M * N;

    const ushort_t* Ab = A + (size_t)blockM * K;
    const ushort_t* Wb = W + (size_t)blockN * K;

    // A staging: 128 rows x 8 chunks = 1024 chunk-slots, 2/thread.
    auto stage_a = [&](int kb, ushort_t* dst) {
#pragma unroll
        for (int it = 0; it < 2; ++it) {
            int s   = it * 512 + t;
            int row = s >> 3, c = s & 7;
            int g   = c ^ (row & 7);
            gload_lds16(Ab + ((size_t)row * K + (kb << 6) + g * 8), dst + s * 8);
        }
    };
    // B staging: 256 rows x 8 chunks = 2048 chunk-slots, 4/thread.
    auto stage_b = [&](int kb, ushort_t* dst) {
#pragma unroll
        for (int it = 0; it < 4; ++it) {
            int s   = it * 512 + t;
            int row = s >> 3, c = s & 7;
            int g   = c ^ (row & 7);
            gload_lds16(Wb + ((size_t)row * K + (kb << 6) + g * 8), dst + s * 8);
        }
    };

    f32x4 acc[8][4];
#pragma unroll
    for (int i = 0; i < 8; ++i)
#pragma unroll
        for (int j = 0; j < 4; ++j) acc[i][j] = (f32x4){0.f, 0.f, 0.f, 0.f};

    // prologue: stage tiles kb0 and kb0+1 into slots 0 and 1 (nt >= 2 always)
    stage_a(kb0, lds);            stage_b(kb0, lds + ASZ);
    stage_a(kb0 + 1, lds + SLOT); stage_b(kb0 + 1, lds + SLOT + ASZ);
    asm volatile("s_waitcnt vmcnt(6)" ::: "memory");   // tile 0 resident
    __builtin_amdgcn_s_barrier();

    const int kc = kg * 4 + q;     // this wave's k-chunk within every BK tile
    int cur = 0;
    for (int tt = 0; tt < nt; ++tt) {
        ushort_t* Ac = lds + cur * SLOT;
        ushort_t* Bc = Ac + ASZ;
        int nx = cur + 2; if (nx >= 3) nx -= 3;
        const bool pre = (tt + 2 < nt);

        // issue next-next tile's staging first (latency hides under compute)
        if (pre) {
            ushort_t* An = lds + nx * SLOT;
            stage_a(kb0 + tt + 2, An);
            stage_b(kb0 + tt + 2, An + ASZ);
        }

        // fragments: 12 ds_read_b128, then 32 MFMA (compiler schedules
        // fine-grained lgkmcnt between them -- proven m97 behavior)
        bf16x8 bfr[4], afr[8];
#pragma unroll
        for (int ni = 0; ni < 4; ++ni) {
            int n = wn * 64 + ni * 16 + l15;
            bfr[ni] = *(const bf16x8*)&Bc[(size_t)(n * 8 + (kc ^ (n & 7))) * 8];
        }
#pragma unroll
        for (int mi = 0; mi < 8; ++mi) {
            int m = mi * 16 + l15;
            afr[mi] = *(const bf16x8*)&Ac[(size_t)(m * 8 + (kc ^ (m & 7))) * 8];
        }
        __builtin_amdgcn_s_setprio(1);
#pragma unroll
        for (int mi = 0; mi < 8; ++mi)
#pragma unroll
            for (int ni = 0; ni < 4; ++ni)
                acc[mi][ni] = __builtin_amdgcn_mfma_f32_16x16x32_bf16(
                    afr[mi], bfr[ni], acc[mi][ni], 0, 0, 0);
        __builtin_amdgcn_s_setprio(0);

        // tile boundary: all LDS reads of slot cur complete (lgkm drain --
        // cheap, reads already consumed by MFMA); keep t+2's 6 loads in
        // flight, require t+1 resident.
        asm volatile("s_waitcnt lgkmcnt(0)" ::: "memory");
        if (pre) asm volatile("s_waitcnt vmcnt(6)" ::: "memory");
        else     asm volatile("s_waitcnt vmcnt(0)" ::: "memory");
        __builtin_amdgcn_s_barrier();

        cur = cur + 1; if (cur == 3) cur = 0;
    }

    // ---- epilogue: sum kg=0/kg=1 partners through LDS, then store ----
    // fp32 scratch [128][257] (pad 257 breaks the q-stride power of 2).
    float* ldsf = (float*)lds;
    if (kg == 1) {
#pragma unroll
        for (int mi = 0; mi < 8; ++mi)
#pragma unroll
            for (int ni = 0; ni < 4; ++ni) {
                int col = wn * 64 + ni * 16 + l15;
#pragma unroll
                for (int r = 0; r < 4; ++r)
                    ldsf[(size_t)(mi * 16 + q * 4 + r) * 257 + col] = acc[mi][ni][r];
            }
    }
    __syncthreads();
    if (kg == 0) {
#pragma unroll
        for (int ni = 0; ni < 4; ++ni) {
            int col = wn * 64 + ni * 16 + l15;
            int n   = blockN + col;
#pragma unroll
            for (int mi = 0; mi < 8; ++mi) {
                int mb = blockM + mi * 16 + q * 4;
#pragma unroll
                for (int r = 0; r < 4; ++r) {
                    float v = acc[mi][ni][r] +
                              ldsf[(size_t)(mi * 16 + q * 4 + r) * 257 + col];
                    Cz[(size_t)(mb + r) * N + n] = v;
                }
            }
        }
    }
}

// ---------------------------------------------------------------------------
// Final: out = gamma*rsqrt(var+eps)*(Q0+Q1+Q2+Q3 - mean) + beta, N=256 cols.
// ---------------------------------------------------------------------------
__global__ __launch_bounds__(256) void bn_reduce_kernel(
    const float4* __restrict__ Q0, const float4* __restrict__ Q1,
    const float4* __restrict__ Q2, const float4* __restrict__ Q3,
    const float* __restrict__ gamma, const float* __restrict__ beta,
    const float* __restrict__ mean,  const float* __restrict__ var,
    float4* __restrict__ out, int n4)
{
    int i = blockIdx.x * 256 + threadIdx.x;
    if (i >= n4) return;
    float4 a = Q0[i], b = Q1[i], c = Q2[i], d = Q3[i];
    int nb = (i * 4) & 255;
    float4 g  = *(const float4*)(gamma + nb);
    float4 be = *(const float4*)(beta + nb);
    float4 mn = *(const float4*)(mean + nb);
    float4 vr = *(const float4*)(var + nb);
    float4 o;
    o.x = g.x * rsqrtf(vr.x + 1e-5f) * (a.x + b.x + c.x + d.x - mn.x) + be.x;
    o.y = g.y * rsqrtf(vr.y + 1e-5f) * (a.y + b.y + c.y + d.y - mn.y) + be.y;
    o.z = g.z * rsqrtf(vr.z + 1e-5f) * (a.z + b.z + c.z + d.z - mn.z) + be.z;
    o.w = g.w * rsqrtf(vr.w + 1e-5f) * (a.w + b.w + c.w + d.w - mn.w) + be.w;
    out[i] = o;
}

// ---------------------------------------------------------------------------
extern "C" void kernel_launch(void* const* d_in, const int* in_sizes, int n_in,
                              void* d_out, int out_size, void* d_ws, size_t ws_size,
                              hipStream_t stream) {
    const float* x     = (const float*)d_in[0];
    const float* bw0   = (const float*)d_in[2];
    const float* sw0   = (const float*)d_in[3];
    const float* bw1   = (const float*)d_in[5];
    const float* sw1   = (const float*)d_in[6];
    const float* bw2   = (const float*)d_in[8];
    const float* sw2   = (const float*)d_in[9];
    const float* gamma = (const float*)d_in[10];
    const float* beta  = (const float*)d_in[11];
    const float* mean  = (const float*)d_in[12];
    const float* var   = (const float*)d_in[13];

    char* ws = (char*)d_ws;
    ushort_t* Abuf = (ushort_t*)(ws);
    ushort_t* W0   = (ushort_t*)(ws + 100663296);
    ushort_t* W1   = (ushort_t*)(ws + 103809024);
    ushort_t* W2   = (ushort_t*)(ws + 110100480);
    float*    P0   = (float*)(ws + 113246208);   // 16 MB (L0/L1 partials)
    float*    P1   = (float*)(ws + 130023424);   // 16 MB
    float*    Q0   = (float*)(ws + 113246208);   // 8 MB (L2 partials x4)
    float*    Q1   = (float*)(ws + 121634816);
    float*    Q2   = (float*)(ws + 130023424);
    float*    Q3   = (float*)(ws + 138412032);
    float*    out  = (float*)d_out;

    const size_t GEMM_LDS = 3 * SLOT * sizeof(ushort_t);  // 147456 B

    // weight packing (d_ws re-poisoned every call -> repack)
    pack_w_kernel<<<(512 * 256 + 255) / 256, 256, 0, stream>>>(bw0, sw0, W0, 512 * 256);
    pack_w_kernel<<<(512 * 512 + 255) / 256, 256, 0, stream>>>(bw1, sw1, W1, 512 * 512);
    pack_w_kernel<<<(256 * 512 + 255) / 256, 256, 0, stream>>>(bw2, sw2, W2, 256 * 512);

    // layer 0: K=3072 (48 chunks, 24/split), N=512, SK=2
    expand_kernel<false><<<4096, 256, 0, stream>>>(x, nullptr, Abuf, 8192 * 256 / 2);
    {
        dim3 g(64, 2, 2);
        gemm_kernel<<<g, 512, GEMM_LDS, stream>>>(Abuf, W0, P0, 8192, 512, 3072, 24);
    }
    // layer 1: K=6144 (96 chunks, 48/split), N=512, SK=2
    expand_kernel<true><<<8192, 256, 0, stream>>>(P0, P1, Abuf, 8192 * 512 / 2);
    {
        dim3 g(64, 2, 2);
        gemm_kernel<<<g, 512, GEMM_LDS, stream>>>(Abuf, W1, P0, 8192, 512, 6144, 48);
    }
    // layer 2: K=6144 (96 chunks, 24/split), N=256, SK=4
    expand_kernel<true><<<8192, 256, 0, stream>>>(P0, P1, Abuf, 8192 * 512 / 2);
    {
        dim3 g(64, 1, 4);
        gemm_kernel<<<g, 512, GEMM_LDS, stream>>>(Abuf, W2, Q0, 8192, 256, 6144, 24);
    }
    // BN + split-K reduce -> out
    bn_reduce_kernel<<<2048, 256, 0, stream>>>(
        (const float4*)Q0, (const float4*)Q1, (const float4*)Q2, (const float4*)Q3,
        gamma, beta, mean, var, (float4*)out, 8192 * 256 / 4);
}